// Round 5
// baseline (234.338 us; speedup 1.0000x reference)
//
#include <hip/hip_runtime.h>
#include <hip/hip_bf16.h>
#include <stdint.h>

typedef __attribute__((ext_vector_type(4))) float f32x4;
typedef __attribute__((ext_vector_type(16))) float f32x16;
typedef __attribute__((ext_vector_type(8))) short s16x8;
typedef __attribute__((ext_vector_type(4))) short s16x4;
typedef __attribute__((ext_vector_type(4))) unsigned int u32x4;

#define DEV static __device__ __forceinline__

constexpr int B_ = 4, H_ = 16, N_ = 2048;
constexpr float CL_ = 0.18033688011112042f;  // dh^-0.5 * log2(e), folded into q

DEV short f2bf(float x) {
  __hip_bfloat16 h = __float2bfloat16(x);
  return *reinterpret_cast<short*>(&h);
}

DEV uint32_t cvtpk(float lo, float hi) {  // packed bf16 (RNE), 1 instr
  uint32_t r;
  asm("v_cvt_pk_bf16_f32 %0, %1, %2" : "=v"(r) : "v"(lo), "v"(hi));
  return r;
}

DEV void gload16(const void* g, void* l) {
  __builtin_amdgcn_global_load_lds((const __attribute__((address_space(1))) void*)g,
                                   (__attribute__((address_space(3))) void*)l, 16, 0, 0);
}

// ---------------- prep: fp32 -> bf16 cast (x) ----------------
__global__ void k_cvt(const float* __restrict__ x, short* __restrict__ xb) {
  int i = (blockIdx.x * 256 + threadIdx.x) * 8;
  const float4* p = reinterpret_cast<const float4*>(x + i);
  float4 a = p[0], b = p[1];
  s16x8 o;
  o[0] = f2bf(a.x); o[1] = f2bf(a.y); o[2] = f2bf(a.z); o[3] = f2bf(a.w);
  o[4] = f2bf(b.x); o[5] = f2bf(b.y); o[6] = f2bf(b.z); o[7] = f2bf(b.w);
  *reinterpret_cast<s16x8*>(xb + i) = o;
}

// ------------- prep: W [R][C] fp32 -> WT [C][R] bf16 -------------
__global__ void k_tw(const float* __restrict__ W, short* __restrict__ WT, int R, int C) {
  __shared__ short t[64][72];
  int r0 = blockIdx.y * 64, c0 = blockIdx.x * 64;
  int tid = threadIdx.x;
  int r = tid >> 2, cp = (tid & 3) * 16;
  const float4* s4 = reinterpret_cast<const float4*>(W + (size_t)(r0 + r) * C + c0 + cp);
  float4 f0 = s4[0], f1 = s4[1], f2 = s4[2], f3 = s4[3];
  short* tr = &t[r][cp];
  tr[0] = f2bf(f0.x); tr[1] = f2bf(f0.y); tr[2]  = f2bf(f0.z); tr[3]  = f2bf(f0.w);
  tr[4] = f2bf(f1.x); tr[5] = f2bf(f1.y); tr[6]  = f2bf(f1.z); tr[7]  = f2bf(f1.w);
  tr[8] = f2bf(f2.x); tr[9] = f2bf(f2.y); tr[10] = f2bf(f2.z); tr[11] = f2bf(f2.w);
  tr[12] = f2bf(f3.x); tr[13] = f2bf(f3.y); tr[14] = f2bf(f3.z); tr[15] = f2bf(f3.w);
  __syncthreads();
  int cc = tid >> 2, rp = (tid & 3) * 16;
  short buf[16];
#pragma unroll
  for (int i = 0; i < 16; ++i) buf[i] = t[rp + i][cc];
  short* dst = WT + (size_t)(c0 + cc) * R + r0 + rp;
  *reinterpret_cast<s16x8*>(dst) = *reinterpret_cast<s16x8*>(buf);
  *reinterpret_cast<s16x8*>(dst + 8) = *reinterpret_cast<s16x8*>(buf + 8);
}

// ------------- transpose v [BH][N][64] -> vT [BH][64][N] -------------
__global__ void k_tv(const short* __restrict__ v, short* __restrict__ vT) {
  __shared__ short t[64][72];
  int bh = blockIdx.y, n0 = blockIdx.x * 64;
  int tid = threadIdx.x;
  int r = tid >> 2, cp = (tid & 3) * 16;
  const short* src = v + ((size_t)bh * N_ + n0 + r) * 64 + cp;
  *reinterpret_cast<s16x8*>(&t[r][cp]) = *reinterpret_cast<const s16x8*>(src);
  *reinterpret_cast<s16x8*>(&t[r][cp + 8]) = *reinterpret_cast<const s16x8*>(src + 8);
  __syncthreads();
  int d = tid >> 2, np = (tid & 3) * 16;
  short buf[16];
#pragma unroll
  for (int i = 0; i < 16; ++i) buf[i] = t[np + i][d];
  short* dst = vT + ((size_t)bh * 64 + d) * N_ + n0 + np;
  *reinterpret_cast<s16x8*>(dst) = *reinterpret_cast<s16x8*>(buf);
  *reinterpret_cast<s16x8*>(dst + 8) = *reinterpret_cast<s16x8*>(buf + 8);
}

// ------------- GEMM: A[M][K] bf16 x BT[N][K] bf16 (m97 structure) -------------
template <int EPI>
__global__ __launch_bounds__(256, 2)
void k_gemm(const short* __restrict__ A, const short* __restrict__ BT,
            int M, int N, int K,
            short* __restrict__ oq, short* __restrict__ ok, short* __restrict__ ov,
            const float* __restrict__ bias, float* __restrict__ out) {
  __shared__ short As[128 * 32];
  __shared__ short Bs[128 * 32];
  const int tid = threadIdx.x;
  const int m0 = blockIdx.x * 128, n0 = blockIdx.y * 128;
  const int lane = tid & 63, w = tid >> 6, g = lane >> 4, c = lane & 15;
  const int wr = w >> 1, wc = w & 1;
  f32x4 acc[4][4] = {};
  const int trow = tid >> 2, tk = (tid & 3) * 8;
  const short* ga = A + (size_t)(m0 + trow) * K + tk;
  const short* gb = BT + (size_t)(n0 + trow) * K + tk;
  short* la = As + tid * 8;
  short* lb = Bs + tid * 8;
  for (int k0 = 0; k0 < K; k0 += 32) {
    gload16(ga + k0, la);
    gload16(ga + (size_t)64 * K + k0, la + 2048);
    gload16(gb + k0, lb);
    gload16(gb + (size_t)64 * K + k0, lb + 2048);
    __syncthreads();
    s16x8 af[4], bf[4];
#pragma unroll
    for (int i = 0; i < 4; ++i)
      af[i] = *reinterpret_cast<const s16x8*>(As + (wr * 64 + i * 16 + c) * 32 + g * 8);
#pragma unroll
    for (int j = 0; j < 4; ++j)
      bf[j] = *reinterpret_cast<const s16x8*>(Bs + (wc * 64 + j * 16 + c) * 32 + g * 8);
#pragma unroll
    for (int i = 0; i < 4; ++i)
#pragma unroll
      for (int j = 0; j < 4; ++j)
        acc[i][j] = __builtin_amdgcn_mfma_f32_16x16x32_bf16(af[i], bf[j], acc[i][j], 0, 0, 0);
    __syncthreads();
  }
  if (EPI == 0) {
#pragma unroll
    for (int bj = 0; bj < 4; ++bj) {
      int ncol = n0 + wc * 64 + bj * 16 + c;
      int part = ncol >> 10;
      int c10 = ncol & 1023;
      int h = c10 >> 6, d = c10 & 63;
      short* dst0 = part == 0 ? oq : (part == 1 ? ok : ov);
      float qs = (part == 0) ? CL_ : 1.0f;
#pragma unroll
      for (int ai = 0; ai < 4; ++ai) {
#pragma unroll
        for (int r = 0; r < 4; ++r) {
          int mrow = m0 + wr * 64 + ai * 16 + g * 4 + r;
          int b = mrow >> 11, nr = mrow & 2047;
          dst0[((size_t)((b * H_ + h) * N_ + nr) << 6) + d] = f2bf(acc[ai][bj][r] * qs);
        }
      }
    }
  } else {
#pragma unroll
    for (int bj = 0; bj < 4; ++bj) {
      int ncol = n0 + wc * 64 + bj * 16 + c;
      float bb = bias[ncol];
#pragma unroll
      for (int ai = 0; ai < 4; ++ai) {
#pragma unroll
        for (int r = 0; r < 4; ++r) {
          int mrow = m0 + wr * 64 + ai * 16 + g * 4 + r;
          out[(size_t)mrow * N + ncol] = acc[ai][bj][r] + bb;
        }
      }
    }
  }
}

// ------------- flash attention, 32x32 MFMA, QBLK=64/wave, fully wave-independent ----
// No LDS / no barriers in the main loop: K and V^T fragments are read per-wave
// straight from global (L2-resident per XCD: 512KB/head x 8 heads = 4MB, proven by
// R4's FETCH=27MB). Waves drift freely so softmax VALU of one wave overlaps MFMA of
// the other resident wave on the SIMD. Software pipeline: QK(kf) -> issue vf ->
// softmax (hides vf) -> issue kf(t+1) (hidden by PV) -> PV.
// Swapped QK^T: S^T = mfma(K,Q); P stays in registers via cvt_pk + permlane32_swap.
__global__ __launch_bounds__(256, 2)
void k_attn(const short* __restrict__ q, const short* __restrict__ kk,
            const short* __restrict__ vT, short* __restrict__ ao) {
  __shared__ __align__(16) short Oq_all[4][2304];  // per-wave epilogue transpose buffer
  int bh = blockIdx.x, qb = blockIdx.y;            // bh fast => same-head blocks on one XCD
  int b = bh >> 4, head = bh & 15;
  int tid = threadIdx.x, w = tid >> 6, lane = tid & 63;
  int half = lane >> 5, qc = lane & 31;
  const size_t ho = (size_t)bh * (N_ * 64);
  const short* Q = q + ho;
  const char* Kc = reinterpret_cast<const char*>(kk + ho);
  const char* Vc = reinterpret_cast<const char*>(vT + ho);
  int q0w = qb * 256 + w * 64;
  // Q B-fragments [i: q 32-block][ks: k 16-slice]: lane holds q=qc, d=ks*16+half*8+e
  s16x8 qf[2][4];
#pragma unroll
  for (int i = 0; i < 2; ++i)
#pragma unroll
    for (int ks = 0; ks < 4; ++ks)
      qf[i][ks] = *reinterpret_cast<const s16x8*>(Q + (size_t)(q0w + i * 32 + qc) * 64 + ks * 16 + half * 8);
  f32x16 ot[2][2] = {};      // O^T accum [d 32-block][q 32-block]
  float lp[2] = {0.f, 0.f};  // per-lane partial exp-sums (this half's kv rows)
  // K A-fragments for tile 0: lane holds kv=j*32+qc, k=ks*16+half*8+e
  s16x8 kf[2][4];
#pragma unroll
  for (int j = 0; j < 2; ++j)
#pragma unroll
    for (int ks = 0; ks < 4; ++ks)
      kf[j][ks] = *reinterpret_cast<const s16x8*>(Kc + (size_t)(j * 32 + qc) * 128 + ks * 32 + half * 16);
  for (int tt = 0; tt < N_ / 64; ++tt) {
    int kv0 = tt * 64;
    f32x16 st[2][2] = {};  // S^T [j kv-blk][i q-blk]
    __builtin_amdgcn_s_setprio(1);
#pragma unroll
    for (int j = 0; j < 2; ++j)
#pragma unroll
      for (int i = 0; i < 2; ++i)
#pragma unroll
        for (int ks = 0; ks < 4; ++ks)
          st[j][i] = __builtin_amdgcn_mfma_f32_32x32x16_bf16(kf[j][ks], qf[i][ks], st[j][i], 0, 0, 0);
    __builtin_amdgcn_s_setprio(0);
    // V^T A-fragments for THIS tile: issue now, latency hides under softmax.
    // lane holds d=db*32+qc, kv=kv0+kb4*16+half*8+e  (V^T row stride = N_*2 = 4096B)
    s16x8 vf[2][4];
#pragma unroll
    for (int db = 0; db < 2; ++db)
#pragma unroll
      for (int kb4 = 0; kb4 < 4; ++kb4)
        vf[db][kb4] = *reinterpret_cast<const s16x8*>(Vc + (size_t)(db * 32 + qc) * 4096 + kv0 * 2 + kb4 * 32 + half * 16);
    // streaming softmax (scores pre-scaled by CL_): exp2, lane-partial sum
#pragma unroll
    for (int j = 0; j < 2; ++j)
#pragma unroll
      for (int i = 0; i < 2; ++i)
#pragma unroll
        for (int r = 0; r < 16; ++r) {
          float p = __builtin_amdgcn_exp2f(st[j][i][r]);
          st[j][i][r] = p;
          lp[i] += p;
        }
    // P -> PV B-fragments in registers: per (j,i,bb): 4 cvtpk + 2 permlane32_swap
    u32x4 pwv[2][4];
#pragma unroll
    for (int j = 0; j < 2; ++j)
#pragma unroll
      for (int i = 0; i < 2; ++i)
#pragma unroll
        for (int bb = 0; bb < 2; ++bb)
#pragma unroll
          for (int p = 0; p < 2; ++p) {
            uint32_t Aw = cvtpk(st[j][i][8 * bb + 2 * p], st[j][i][8 * bb + 2 * p + 1]);
            uint32_t Bw = cvtpk(st[j][i][8 * bb + 4 + 2 * p], st[j][i][8 * bb + 4 + 2 * p + 1]);
            asm volatile("v_permlane32_swap_b32 %0, %1" : "+v"(Aw), "+v"(Bw));
            pwv[i][j * 2 + bb][p] = Aw;       // word m = p
            pwv[i][j * 2 + bb][p + 2] = Bw;   // word m = p + 2
          }
    // prefetch K fragments for next tile (kf regs dead after QK; hidden by PV)
    if (tt + 1 < N_ / 64) {
#pragma unroll
      for (int j = 0; j < 2; ++j)
#pragma unroll
        for (int ks = 0; ks < 4; ++ks)
          kf[j][ks] = *reinterpret_cast<const s16x8*>(Kc + (size_t)((tt + 1) * 64 + j * 32 + qc) * 128 + ks * 32 + half * 16);
    }
    __builtin_amdgcn_s_setprio(1);
#pragma unroll
    for (int db = 0; db < 2; ++db)
#pragma unroll
      for (int i = 0; i < 2; ++i)
#pragma unroll
        for (int kb4 = 0; kb4 < 4; ++kb4)
          ot[db][i] = __builtin_amdgcn_mfma_f32_32x32x16_bf16(
              vf[db][kb4], __builtin_bit_cast(s16x8, pwv[i][kb4]), ot[db][i], 0, 0, 0);
    __builtin_amdgcn_s_setprio(0);
  }
  // l: this lane's half + partner half
  float inv[2];
#pragma unroll
  for (int i = 0; i < 2; ++i) {
    float t = lp[i] + __shfl_xor(lp[i], 32, 64);
    inv[i] = 1.f / t;
  }
  // epilogue: per-wave LDS region, wave-coherent (no barriers needed)
  short* Oq = Oq_all[w];  // [32][72]
#pragma unroll
  for (int i = 0; i < 2; ++i) {
#pragma unroll
    for (int db = 0; db < 2; ++db)
#pragma unroll
      for (int m = 0; m < 4; ++m) {
        uint2 pk;
        pk.x = cvtpk(ot[db][i][4 * m] * inv[i], ot[db][i][4 * m + 1] * inv[i]);
        pk.y = cvtpk(ot[db][i][4 * m + 2] * inv[i], ot[db][i][4 * m + 3] * inv[i]);
        *reinterpret_cast<uint2*>(Oq + qc * 72 + db * 32 + m * 8 + half * 4) = pk;
      }
    int q2 = lane >> 1, dcol = (lane & 1) * 32;
    size_t ro = (size_t)(b * N_ + q0w + i * 32 + q2) * 1024 + head * 64 + dcol;
#pragma unroll
    for (int ch = 0; ch < 4; ++ch) {
      s16x8 vv = *reinterpret_cast<const s16x8*>(Oq + q2 * 72 + dcol + ch * 8);
      *reinterpret_cast<s16x8*>(ao + ro + ch * 8) = vv;
    }
  }
}

extern "C" void kernel_launch(void* const* d_in, const int* in_sizes, int n_in,
                              void* d_out, int out_size, void* d_ws, size_t ws_size,
                              hipStream_t stream) {
  const float* x = (const float*)d_in[0];
  const float* w_qkv = (const float*)d_in[1];
  const float* w_out = (const float*)d_in[2];
  const float* b_out = (const float*)d_in[3];
  float* out = (float*)d_out;
  char* ws = (char*)d_ws;
  short* xb    = (short*)(ws);                // [8192][1024] bf16 (reused as ao later)
  short* wqkvT = (short*)(ws + 16777216);     // [3072][1024]
  short* woutT = (short*)(ws + 23068672);     // [1024][1024]
  short* qB    = (short*)(ws + 25165824);     // [B][H][N][64] (pre-scaled by CL_)
  short* kB    = (short*)(ws + 41943040);
  short* vtmp  = (short*)(ws + 58720256);
  short* vTT   = (short*)(ws + 75497472);     // [B][H][64][N]
  short* ao    = xb;                          // alias: xb dead after gemm<0>

  k_cvt<<<4096, 256, 0, stream>>>(x, xb);
  k_tw<<<dim3(48, 16), 256, 0, stream>>>(w_qkv, wqkvT, 1024, 3072);
  k_tw<<<dim3(16, 16), 256, 0, stream>>>(w_out, woutT, 1024, 1024);
  k_gemm<0><<<dim3(64, 24), 256, 0, stream>>>(xb, wqkvT, 8192, 3072, 1024,
                                              qB, kB, vtmp, nullptr, nullptr);
  k_tv<<<dim3(32, 64), 256, 0, stream>>>(vtmp, vTT);
  k_attn<<<dim3(64, 8), 256, 0, stream>>>(qB, kB, vTT, ao);
  k_gemm<1><<<dim3(64, 8), 256, 0, stream>>>(ao, woutT, 8192, 1024, 1024,
                                             nullptr, nullptr, nullptr, b_out, out);
}

// Round 6
// 191.808 us; speedup vs baseline: 1.2217x; 1.2217x over previous
//
#include <hip/hip_runtime.h>
#include <hip/hip_bf16.h>
#include <stdint.h>

typedef __attribute__((ext_vector_type(4))) float f32x4;
typedef __attribute__((ext_vector_type(16))) float f32x16;
typedef __attribute__((ext_vector_type(8))) short s16x8;
typedef __attribute__((ext_vector_type(4))) short s16x4;
typedef __attribute__((ext_vector_type(4))) unsigned int u32x4;

#define DEV static __device__ __forceinline__

constexpr int B_ = 4, H_ = 16, N_ = 2048;
constexpr float CL_ = 0.18033688011112042f;  // dh^-0.5 * log2(e), folded into q

DEV short f2bf(float x) {
  __hip_bfloat16 h = __float2bfloat16(x);
  return *reinterpret_cast<short*>(&h);
}

DEV uint32_t cvtpk(float lo, float hi) {  // packed bf16 (RNE), 1 instr
  uint32_t r;
  asm("v_cvt_pk_bf16_f32 %0, %1, %2" : "=v"(r) : "v"(lo), "v"(hi));
  return r;
}

DEV void gload16(const void* g, void* l) {
  __builtin_amdgcn_global_load_lds((const __attribute__((address_space(1))) void*)g,
                                   (__attribute__((address_space(3))) void*)l, 16, 0, 0);
}

// ---------------- prep: fp32 -> bf16 cast (x) ----------------
__global__ void k_cvt(const float* __restrict__ x, short* __restrict__ xb) {
  int i = (blockIdx.x * 256 + threadIdx.x) * 8;
  const float4* p = reinterpret_cast<const float4*>(x + i);
  float4 a = p[0], b = p[1];
  s16x8 o;
  o[0] = f2bf(a.x); o[1] = f2bf(a.y); o[2] = f2bf(a.z); o[3] = f2bf(a.w);
  o[4] = f2bf(b.x); o[5] = f2bf(b.y); o[6] = f2bf(b.z); o[7] = f2bf(b.w);
  *reinterpret_cast<s16x8*>(xb + i) = o;
}

// ------------- prep: W [R][C] fp32 -> WT [C][R] bf16 -------------
__global__ void k_tw(const float* __restrict__ W, short* __restrict__ WT, int R, int C) {
  __shared__ short t[64][72];
  int r0 = blockIdx.y * 64, c0 = blockIdx.x * 64;
  int tid = threadIdx.x;
  int r = tid >> 2, cp = (tid & 3) * 16;
  const float4* s4 = reinterpret_cast<const float4*>(W + (size_t)(r0 + r) * C + c0 + cp);
  float4 f0 = s4[0], f1 = s4[1], f2 = s4[2], f3 = s4[3];
  short* tr = &t[r][cp];
  tr[0] = f2bf(f0.x); tr[1] = f2bf(f0.y); tr[2]  = f2bf(f0.z); tr[3]  = f2bf(f0.w);
  tr[4] = f2bf(f1.x); tr[5] = f2bf(f1.y); tr[6]  = f2bf(f1.z); tr[7]  = f2bf(f1.w);
  tr[8] = f2bf(f2.x); tr[9] = f2bf(f2.y); tr[10] = f2bf(f2.z); tr[11] = f2bf(f2.w);
  tr[12] = f2bf(f3.x); tr[13] = f2bf(f3.y); tr[14] = f2bf(f3.z); tr[15] = f2bf(f3.w);
  __syncthreads();
  int cc = tid >> 2, rp = (tid & 3) * 16;
  short buf[16];
#pragma unroll
  for (int i = 0; i < 16; ++i) buf[i] = t[rp + i][cc];
  short* dst = WT + (size_t)(c0 + cc) * R + r0 + rp;
  *reinterpret_cast<s16x8*>(dst) = *reinterpret_cast<s16x8*>(buf);
  *reinterpret_cast<s16x8*>(dst + 8) = *reinterpret_cast<s16x8*>(buf + 8);
}

// ------------- transpose v [BH][N][64] -> vT [BH][64][N] -------------
__global__ void k_tv(const short* __restrict__ v, short* __restrict__ vT) {
  __shared__ short t[64][72];
  int bh = blockIdx.y, n0 = blockIdx.x * 64;
  int tid = threadIdx.x;
  int r = tid >> 2, cp = (tid & 3) * 16;
  const short* src = v + ((size_t)bh * N_ + n0 + r) * 64 + cp;
  *reinterpret_cast<s16x8*>(&t[r][cp]) = *reinterpret_cast<const s16x8*>(src);
  *reinterpret_cast<s16x8*>(&t[r][cp + 8]) = *reinterpret_cast<const s16x8*>(src + 8);
  __syncthreads();
  int d = tid >> 2, np = (tid & 3) * 16;
  short buf[16];
#pragma unroll
  for (int i = 0; i < 16; ++i) buf[i] = t[np + i][d];
  short* dst = vT + ((size_t)bh * 64 + d) * N_ + n0 + np;
  *reinterpret_cast<s16x8*>(dst) = *reinterpret_cast<s16x8*>(buf);
  *reinterpret_cast<s16x8*>(dst + 8) = *reinterpret_cast<s16x8*>(buf + 8);
}

// ------------- GEMM: A[M][K] bf16 x BT[N][K] bf16 (m97 structure) -------------
template <int EPI>
__global__ __launch_bounds__(256, 2)
void k_gemm(const short* __restrict__ A, const short* __restrict__ BT,
            int M, int N, int K,
            short* __restrict__ oq, short* __restrict__ ok, short* __restrict__ ov,
            const float* __restrict__ bias, float* __restrict__ out) {
  __shared__ short As[128 * 32];
  __shared__ short Bs[128 * 32];
  const int tid = threadIdx.x;
  const int m0 = blockIdx.x * 128, n0 = blockIdx.y * 128;
  const int lane = tid & 63, w = tid >> 6, g = lane >> 4, c = lane & 15;
  const int wr = w >> 1, wc = w & 1;
  f32x4 acc[4][4] = {};
  const int trow = tid >> 2, tk = (tid & 3) * 8;
  const short* ga = A + (size_t)(m0 + trow) * K + tk;
  const short* gb = BT + (size_t)(n0 + trow) * K + tk;
  short* la = As + tid * 8;
  short* lb = Bs + tid * 8;
  for (int k0 = 0; k0 < K; k0 += 32) {
    gload16(ga + k0, la);
    gload16(ga + (size_t)64 * K + k0, la + 2048);
    gload16(gb + k0, lb);
    gload16(gb + (size_t)64 * K + k0, lb + 2048);
    __syncthreads();
    s16x8 af[4], bf[4];
#pragma unroll
    for (int i = 0; i < 4; ++i)
      af[i] = *reinterpret_cast<const s16x8*>(As + (wr * 64 + i * 16 + c) * 32 + g * 8);
#pragma unroll
    for (int j = 0; j < 4; ++j)
      bf[j] = *reinterpret_cast<const s16x8*>(Bs + (wc * 64 + j * 16 + c) * 32 + g * 8);
#pragma unroll
    for (int i = 0; i < 4; ++i)
#pragma unroll
      for (int j = 0; j < 4; ++j)
        acc[i][j] = __builtin_amdgcn_mfma_f32_16x16x32_bf16(af[i], bf[j], acc[i][j], 0, 0, 0);
    __syncthreads();
  }
  if (EPI == 0) {
#pragma unroll
    for (int bj = 0; bj < 4; ++bj) {
      int ncol = n0 + wc * 64 + bj * 16 + c;
      int part = ncol >> 10;
      int c10 = ncol & 1023;
      int h = c10 >> 6, d = c10 & 63;
      short* dst0 = part == 0 ? oq : (part == 1 ? ok : ov);
      float qs = (part == 0) ? CL_ : 1.0f;
#pragma unroll
      for (int ai = 0; ai < 4; ++ai) {
#pragma unroll
        for (int r = 0; r < 4; ++r) {
          int mrow = m0 + wr * 64 + ai * 16 + g * 4 + r;
          int b = mrow >> 11, nr = mrow & 2047;
          dst0[((size_t)((b * H_ + h) * N_ + nr) << 6) + d] = f2bf(acc[ai][bj][r] * qs);
        }
      }
    }
  } else {
#pragma unroll
    for (int bj = 0; bj < 4; ++bj) {
      int ncol = n0 + wc * 64 + bj * 16 + c;
      float bb = bias[ncol];
#pragma unroll
      for (int ai = 0; ai < 4; ++ai) {
#pragma unroll
        for (int r = 0; r < 4; ++r) {
          int mrow = m0 + wr * 64 + ai * 16 + g * 4 + r;
          out[(size_t)mrow * N + ncol] = acc[ai][bj][r] + bb;
        }
      }
    }
  }
}

// ------------- flash attention: 32x32 MFMA, QBLK=64/wave, deep-pipelined LDS staging ----
// R4 structure + T4: 4-slot LDS rotation staged 2 tiles ahead, raw s_barrier with
// COUNTED s_waitcnt vmcnt(8) (never drain to 0 in the main loop). One barrier/tile.
// Swapped QK^T (S^T = mfma(K,Q)); P stays in registers via cvt_pk + permlane32_swap.
__global__ __launch_bounds__(256, 2)
void k_attn(const short* __restrict__ q, const short* __restrict__ kk,
            const short* __restrict__ vT, short* __restrict__ ao) {
  // 4 x 16KB staging slots (K 8K + V 8K each). Epilogue Oq reuses [0, 18432).
  __shared__ __align__(16) char smem[65536];
  constexpr int NT = N_ / 64;  // 32 kv tiles
  int bh = blockIdx.x, qb = blockIdx.y;  // bh fast => same-head blocks on one XCD
  int b = bh >> 4, head = bh & 15;
  int tid = threadIdx.x, w = tid >> 6, lane = tid & 63;
  int half = lane >> 5, qc = lane & 31;
  const size_t ho = (size_t)bh * (N_ * 64);
  const short* Q = q + ho;
  const char* Kc = reinterpret_cast<const char*>(kk + ho);
  const char* Vc = reinterpret_cast<const char*>(vT + ho);
  int q0w = qb * 256 + w * 64;
  // Q B-fragments [i: q 32-block][ks: k 16-slice]: lane holds q=qc, d=ks*16+half*8+e
  s16x8 qf[2][4];
#pragma unroll
  for (int i = 0; i < 2; ++i)
#pragma unroll
    for (int ks = 0; ks < 4; ++ks)
      qf[i][ks] = *reinterpret_cast<const s16x8*>(Q + (size_t)(q0w + i * 32 + qc) * 64 + ks * 16 + half * 8);
  f32x16 ot[2][2] = {};      // O^T accum [d 32-block][q 32-block]
  float lp[2] = {0.f, 0.f};  // per-lane partial exp-sums (this half's kv rows)
  const int rsw = (qc & 7) << 4;  // read-side XOR swizzle
  // staging geometry: 1024 16B chunks per 16KB slot; this thread's 4 chunks
  const int s_i0 = tid, s_i1 = tid + 256;
  const int s_r0 = s_i0 >> 3, s_c0 = ((s_i0 & 7) << 4) ^ ((s_r0 & 7) << 4);
  const int s_r1 = s_i1 >> 3, s_c1 = ((s_i1 & 7) << 4) ^ ((s_r1 & 7) << 4);
#define STAGE(T)                                                                       \
  {                                                                                    \
    char* nb = smem + ((T) & 3) * 16384;                                               \
    gload16(Kc + (size_t)((T) * 64 + s_r0) * 128 + s_c0, nb + s_i0 * 16);              \
    gload16(Kc + (size_t)((T) * 64 + s_r1) * 128 + s_c1, nb + s_i1 * 16);              \
    gload16(Vc + (size_t)s_r0 * 4096 + (T) * 128 + s_c0, nb + 8192 + s_i0 * 16);       \
    gload16(Vc + (size_t)s_r1 * 4096 + (T) * 128 + s_c1, nb + 8192 + s_i1 * 16);       \
  }
  // prologue: tiles 0 and 1 (8 loads in flight)
  STAGE(0);
  STAGE(1);
  for (int tt = 0; tt < NT; ++tt) {
    if (tt + 2 < NT) STAGE(tt + 2);
    // own stage(tt) complete (leave tt+1, tt+2 in flight), then cross-wave barrier
    if (tt + 2 < NT) {
      asm volatile("s_waitcnt vmcnt(8)" ::: "memory");
    } else if (tt + 1 < NT) {
      asm volatile("s_waitcnt vmcnt(4)" ::: "memory");
    } else {
      asm volatile("s_waitcnt vmcnt(0)" ::: "memory");
    }
    __builtin_amdgcn_s_barrier();
    __builtin_amdgcn_sched_barrier(0);
    const char* kb_ = smem + (tt & 3) * 16384;
    const char* vb_ = kb_ + 8192;
    // K A-fragments [j: kv 32-block][ks]: lane holds kv=j*32+qc, k=ks*16+half*8+e
    s16x8 kf[2][4];
#pragma unroll
    for (int j = 0; j < 2; ++j)
#pragma unroll
      for (int ks = 0; ks < 4; ++ks)
        kf[j][ks] = *reinterpret_cast<const s16x8*>(kb_ + (j * 32 + qc) * 128 + ((ks * 32 + half * 16) ^ rsw));
    f32x16 st[2][2] = {};  // S^T [j kv-blk][i q-blk]
    __builtin_amdgcn_s_setprio(1);
#pragma unroll
    for (int j = 0; j < 2; ++j)
#pragma unroll
      for (int i = 0; i < 2; ++i)
#pragma unroll
        for (int ks = 0; ks < 4; ++ks)
          st[j][i] = __builtin_amdgcn_mfma_f32_32x32x16_bf16(kf[j][ks], qf[i][ks], st[j][i], 0, 0, 0);
    __builtin_amdgcn_s_setprio(0);
    // streaming softmax (scores pre-scaled by CL_): exp2, lane-partial sum
#pragma unroll
    for (int j = 0; j < 2; ++j)
#pragma unroll
      for (int i = 0; i < 2; ++i)
#pragma unroll
        for (int r = 0; r < 16; ++r) {
          float p = __builtin_amdgcn_exp2f(st[j][i][r]);
          st[j][i][r] = p;
          lp[i] += p;
        }
    // P -> PV B-fragments in registers: per (j,i,bb): 4 cvtpk + 2 permlane32_swap
    u32x4 pwv[2][4];
#pragma unroll
    for (int j = 0; j < 2; ++j)
#pragma unroll
      for (int i = 0; i < 2; ++i)
#pragma unroll
        for (int bb = 0; bb < 2; ++bb)
#pragma unroll
          for (int p = 0; p < 2; ++p) {
            uint32_t Aw = cvtpk(st[j][i][8 * bb + 2 * p], st[j][i][8 * bb + 2 * p + 1]);
            uint32_t Bw = cvtpk(st[j][i][8 * bb + 4 + 2 * p], st[j][i][8 * bb + 4 + 2 * p + 1]);
            asm volatile("v_permlane32_swap_b32 %0, %1" : "+v"(Aw), "+v"(Bw));
            pwv[i][j * 2 + bb][p] = Aw;       // word m = p
            pwv[i][j * 2 + bb][p + 2] = Bw;   // word m = p + 2
          }
    // V^T A-fragments [db: d 32-block][kb4: kv 16-block]: lane holds d=db*32+qc
    s16x8 vf[2][4];
#pragma unroll
    for (int db = 0; db < 2; ++db)
#pragma unroll
      for (int kb4 = 0; kb4 < 4; ++kb4)
        vf[db][kb4] = *reinterpret_cast<const s16x8*>(vb_ + (db * 32 + qc) * 128 + ((kb4 * 32 + half * 16) ^ rsw));
    __builtin_amdgcn_s_setprio(1);
#pragma unroll
    for (int db = 0; db < 2; ++db)
#pragma unroll
      for (int i = 0; i < 2; ++i)
#pragma unroll
        for (int kb4 = 0; kb4 < 4; ++kb4)
          ot[db][i] = __builtin_amdgcn_mfma_f32_32x32x16_bf16(
              vf[db][kb4], __builtin_bit_cast(s16x8, pwv[i][kb4]), ot[db][i], 0, 0, 0);
    __builtin_amdgcn_s_setprio(0);
  }
#undef STAGE
  // l: this lane's half + partner half
  float inv[2];
#pragma unroll
  for (int i = 0; i < 2; ++i) {
    float t = lp[i] + __shfl_xor(lp[i], 32, 64);
    inv[i] = 1.f / t;
  }
  // epilogue: per-wave LDS region in [0, 18432) — slot3 (last-read buffer) untouched
  short* Oq = reinterpret_cast<short*>(smem) + w * 2304;  // [32][72]
#pragma unroll
  for (int i = 0; i < 2; ++i) {
#pragma unroll
    for (int db = 0; db < 2; ++db)
#pragma unroll
      for (int m = 0; m < 4; ++m) {
        uint2 pk;
        pk.x = cvtpk(ot[db][i][4 * m] * inv[i], ot[db][i][4 * m + 1] * inv[i]);
        pk.y = cvtpk(ot[db][i][4 * m + 2] * inv[i], ot[db][i][4 * m + 3] * inv[i]);
        *reinterpret_cast<uint2*>(Oq + qc * 72 + db * 32 + m * 8 + half * 4) = pk;
      }
    int q2 = lane >> 1, dcol = (lane & 1) * 32;
    size_t ro = (size_t)(b * N_ + q0w + i * 32 + q2) * 1024 + head * 64 + dcol;
#pragma unroll
    for (int ch = 0; ch < 4; ++ch) {
      s16x8 vv = *reinterpret_cast<const s16x8*>(Oq + q2 * 72 + dcol + ch * 8);
      *reinterpret_cast<s16x8*>(ao + ro + ch * 8) = vv;
    }
  }
}

extern "C" void kernel_launch(void* const* d_in, const int* in_sizes, int n_in,
                              void* d_out, int out_size, void* d_ws, size_t ws_size,
                              hipStream_t stream) {
  const float* x = (const float*)d_in[0];
  const float* w_qkv = (const float*)d_in[1];
  const float* w_out = (const float*)d_in[2];
  const float* b_out = (const float*)d_in[3];
  float* out = (float*)d_out;
  char* ws = (char*)d_ws;
  short* xb    = (short*)(ws);                // [8192][1024] bf16 (reused as ao later)
  short* wqkvT = (short*)(ws + 16777216);     // [3072][1024]
  short* woutT = (short*)(ws + 23068672);     // [1024][1024]
  short* qB    = (short*)(ws + 25165824);     // [B][H][N][64] (pre-scaled by CL_)
  short* kB    = (short*)(ws + 41943040);
  short* vtmp  = (short*)(ws + 58720256);
  short* vTT   = (short*)(ws + 75497472);     // [B][H][64][N]
  short* ao    = xb;                          // alias: xb dead after gemm<0>

  k_cvt<<<4096, 256, 0, stream>>>(x, xb);
  k_tw<<<dim3(48, 16), 256, 0, stream>>>(w_qkv, wqkvT, 1024, 3072);
  k_tw<<<dim3(16, 16), 256, 0, stream>>>(w_out, woutT, 1024, 1024);
  k_gemm<0><<<dim3(64, 24), 256, 0, stream>>>(xb, wqkvT, 8192, 3072, 1024,
                                              qB, kB, vtmp, nullptr, nullptr);
  k_tv<<<dim3(32, 64), 256, 0, stream>>>(vtmp, vTT);
  k_attn<<<dim3(64, 8), 256, 0, stream>>>(qB, kB, vTT, ao);
  k_gemm<1><<<dim3(64, 8), 256, 0, stream>>>(ao, woutT, 8192, 1024, 1024,
                                             nullptr, nullptr, nullptr, b_out, out);
}